// Round 22
// baseline (100.595 us; speedup 1.0000x reference)
//
#include <hip/hip_runtime.h>
#include <hip/hip_fp16.h>
#include <cmath>

// Problem constants: B=4, S=1024, NX=1024, NH=16, HD=64
constexpr int Bb  = 4;
constexpr int Ss  = 1024;
constexpr int NXc = 1024;
constexpr int NHc = 16;
constexpr int HDc = 64;

typedef __bf16    bf16x8 __attribute__((ext_vector_type(8)));
typedef _Float16  f16x8  __attribute__((ext_vector_type(8)));
typedef float     f32x4  __attribute__((ext_vector_type(4)));
typedef unsigned short ushortT;
typedef ushortT ushort8v __attribute__((ext_vector_type(8)));
typedef unsigned uint2v  __attribute__((ext_vector_type(2)));

// Q pre-scale: (1/sqrt(64)) * log2(e) -> softmax via single v_exp_f32 (exp2)
#define QSCALE 0.18033688011112042f

// ---------------------------------------------------------------------------
// helpers
// ---------------------------------------------------------------------------
__device__ __forceinline__ ushortT f2h_bits(float x) {
  return __half_as_ushort(__float2half(x));   // RNE, single v_cvt_f16_f32
}

// async global->LDS, 16 bytes per lane
__device__ __forceinline__ void gll16(const void* g, void* l) {
  __builtin_amdgcn_global_load_lds(
      (const __attribute__((address_space(1))) unsigned int*)g,
      (__attribute__((address_space(3))) unsigned int*)l, 16, 0, 0);
}

// explicit drain of all outstanding VMEM (incl. global_load_lds DMA)
__device__ __forceinline__ void drain_vmem() {
  asm volatile("s_waitcnt vmcnt(0)" ::: "memory");
  __builtin_amdgcn_sched_barrier(0);
}

// ---------------------------------------------------------------------------
// Fused prep kernel (deterministic: block-local, uniform branches):
//   blocks [0,4096):     hs fp32 -> fp16 (hF)
//   blocks [4096,7168):  aw [1024][3072] -> transposed fp16 awT [3072][1024]
//   blocks [7168,8192):  pw [1024][1024] -> transposed fp16 pwT [1024][1024]
// ---------------------------------------------------------------------------
__global__ __launch_bounds__(256) void prep_all(
    const float* __restrict__ hs, const float* __restrict__ aw,
    const float* __restrict__ pw,
    ushortT* __restrict__ hF, ushortT* __restrict__ awT,
    ushortT* __restrict__ pwT)
{
  const int bid = blockIdx.x;
  if (bid < 4096) {
    int i = (bid * 256 + threadIdx.x) * 4;
    float4 v = *reinterpret_cast<const float4*>(&hs[i]);
    *reinterpret_cast<ushort4*>(&hF[i]) =
        make_ushort4(f2h_bits(v.x), f2h_bits(v.y), f2h_bits(v.z), f2h_bits(v.w));
    return;
  }
  __shared__ float tile[32][33];
  const int tx = threadIdx.x & 31, ty = threadIdx.x >> 5;  // 32 x 8
  if (bid < 7168) {
    // aw transpose: K=1024, N=3072
    const int b2 = bid - 4096;
    const int n0 = (b2 % 96) * 32, k0 = (b2 / 96) * 32;
    #pragma unroll
    for (int i = 0; i < 4; ++i)
      tile[ty + i * 8][tx] = aw[(size_t)(k0 + ty + i * 8) * 3072 + n0 + tx];
    __syncthreads();
    #pragma unroll
    for (int i = 0; i < 4; ++i)
      awT[(size_t)(n0 + ty + i * 8) * 1024 + k0 + tx] = f2h_bits(tile[tx][ty + i * 8]);
  } else {
    // pw transpose: K=1024, N=1024
    const int b2 = bid - 7168;
    const int n0 = (b2 & 31) * 32, k0 = (b2 >> 5) * 32;
    #pragma unroll
    for (int i = 0; i < 4; ++i)
      tile[ty + i * 8][tx] = pw[(size_t)(k0 + ty + i * 8) * 1024 + n0 + tx];
    __syncthreads();
    #pragma unroll
    for (int i = 0; i < 4; ++i)
      pwT[(size_t)(n0 + ty + i * 8) * 1024 + k0 + tx] = f2h_bits(tile[tx][ty + i * 8]);
  }
}

// ---------------------------------------------------------------------------
// Single-pass fp16 MFMA GEMM with fused QKV epilogue (R19-R21-verified,
// incl. XCD-bijective swizzle). Outputs fp16 Qb (x QSCALE), Kb, Vt.
// ---------------------------------------------------------------------------
__global__ __launch_bounds__(256) void gemm_f16_qkv(
    const ushortT* __restrict__ A16, const ushortT* __restrict__ B16,
    const float* __restrict__ bias,
    ushortT* __restrict__ Qb, ushortT* __restrict__ Kb,
    ushortT* __restrict__ Vt, int M, int N, int K)
{
  constexpr int BK = 64;
  __shared__ ushortT smem[32768];   // 64 KB: buf0 [0,16384), buf1 [16384,32768)

  const int t    = threadIdx.x;
  const int lane = t & 63;
  const int w    = t >> 6;
  const int wr   = w >> 1, wc = w & 1;
  const int lin = blockIdx.y * 24 + blockIdx.x;           // 0..767
  const int swz = (lin & 7) * 96 + (lin >> 3);
  const int m0 = (swz / 24) * 128;
  const int n0 = (swz % 24) * 128;
  const int l15 = lane & 15;
  const int g   = lane >> 4;

  const int srow  = w * 32 + (lane >> 3);
  const int sslot = (lane & 7) ^ (lane >> 3);

  f32x4 acc[4][4];
  #pragma unroll
  for (int m = 0; m < 4; ++m)
    #pragma unroll
    for (int n = 0; n < 4; ++n)
      #pragma unroll
      for (int r = 0; r < 4; ++r) acc[m][n][r] = 0.f;

  const ushortT* pA = A16 + (size_t)(m0 + srow) * K + sslot * 8;
  const ushortT* pB = B16 + (size_t)(n0 + srow) * K + sslot * 8;

  auto STAGE = [&](ushortT* buf, int k0) {
    #pragma unroll
    for (int i = 0; i < 4; ++i) {
      const size_t gstep = (size_t)i * 8 * K + k0;
      const int    loff  = (w * 32 + i * 8) * BK;
      gll16(pA + gstep, &buf[loff]);
      gll16(pB + gstep, &buf[8192 + loff]);
    }
  };

  const int arow = wr * 64 + l15;
  const int bcol = wc * 64 + l15;

  auto COMPUTE = [&](const ushortT* buf) {
    const ushortT* sA = buf;
    const ushortT* sB = buf + 8192;
    #pragma unroll
    for (int c = 0; c < 2; ++c) {
      const int slot = c * 4 + g;
      f16x8 af[4], bf[4];
      #pragma unroll
      for (int m = 0; m < 4; ++m) {
        int r   = arow + m * 16;
        int off = r * BK + ((slot ^ (r & 7)) * 8);
        af[m] = *reinterpret_cast<const f16x8*>(&sA[off]);
      }
      #pragma unroll
      for (int n = 0; n < 4; ++n) {
        int r   = bcol + n * 16;
        int off = r * BK + ((slot ^ (r & 7)) * 8);
        bf[n] = *reinterpret_cast<const f16x8*>(&sB[off]);
      }
      #pragma unroll
      for (int m = 0; m < 4; ++m)
        #pragma unroll
        for (int n = 0; n < 4; ++n)
          acc[m][n] = __builtin_amdgcn_mfma_f32_16x16x32_f16(af[m], bf[n], acc[m][n], 0, 0, 0);
    }
  };

  const int nt = K / BK;
  STAGE(&smem[0], 0);
  drain_vmem();
  __syncthreads();
  for (int tt = 0; tt < nt; tt += 2) {
    if (tt + 1 < nt) STAGE(&smem[16384], (tt + 1) * BK);
    COMPUTE(&smem[0]);
    drain_vmem();
    __syncthreads();
    if (tt + 2 < nt) STAGE(&smem[0], (tt + 2) * BK);
    COMPUTE(&smem[16384]);
    drain_vmem();
    __syncthreads();
  }

  const int region = n0 >> 10;   // 0=Q, 1=K, 2=V
  if (region < 2) {
    #pragma unroll
    for (int n = 0; n < 4; ++n) {
      int col_g = n0 + wc * 64 + n * 16 + l15;
      int colm  = col_g & 1023;
      float bv  = bias[col_g];
      #pragma unroll
      for (int m = 0; m < 4; ++m) {
        int row = m0 + wr * 64 + m * 16 + (g << 2);
        #pragma unroll
        for (int r = 0; r < 4; ++r) {
          float v = acc[m][n][r] + bv;
          if (region == 0)
            Qb[(size_t)(row + r) * 1024 + colm] = f2h_bits(v * QSCALE);
          else
            Kb[(size_t)(row + r) * 1024 + colm] = f2h_bits(v);
        }
      }
    }
  } else {
    ushortT* T = smem;   // [128 cols][136] = 34816 B <= 64 KB
    #pragma unroll
    for (int n = 0; n < 4; ++n) {
      int cl   = wc * 64 + n * 16 + l15;
      float bv = bias[n0 + cl];
      #pragma unroll
      for (int m = 0; m < 4; ++m) {
        int rl = wr * 64 + m * 16 + (g << 2);
        #pragma unroll
        for (int r = 0; r < 4; ++r)
          T[cl * 136 + rl + r] = f2h_bits(acc[m][n][r] + bv);
      }
    }
    __syncthreads();
    const int c  = t >> 1;
    const int rh = (t & 1) * 64;
    const int nn = (n0 - 2048) + c;
    const int hh = nn >> 6, dd = nn & 63;
    const int bb = m0 >> 10;
    const int sl = (m0 & 1023) + rh;
    size_t vbase = ((size_t)((bb * 16 + hh) * 64 + dd)) * 1024 + sl;
    #pragma unroll
    for (int j = 0; j < 8; ++j) {
      ushort8v v = *reinterpret_cast<const ushort8v*>(&T[c * 136 + rh + j * 8]);
      *reinterpret_cast<ushort8v*>(&Vt[vbase + j * 8]) = v;
    }
  }
}

// ---------------------------------------------------------------------------
// Single-pass fp16 MFMA GEMM (proj), 2-phase dbuf + XCD swizzle (R19-R21).
// ---------------------------------------------------------------------------
__global__ __launch_bounds__(256) void gemm_f16s(
    const ushortT* __restrict__ A16, const ushortT* __restrict__ B16,
    const float* __restrict__ bias, float* __restrict__ C,
    int M, int N, int K)
{
  constexpr int BK = 64;
  __shared__ ushortT smem[32768];   // 64 KB: two 32KB buffers

  const int t    = threadIdx.x;
  const int lane = t & 63;
  const int w    = t >> 6;
  const int wr   = w >> 1, wc = w & 1;
  const int lin = blockIdx.y * 8 + blockIdx.x;            // 0..255
  const int swz = (lin & 7) * 32 + (lin >> 3);
  const int m0 = (swz / 8) * 128;
  const int n0 = (swz % 8) * 128;
  const int l15 = lane & 15;
  const int g   = lane >> 4;

  const int srow  = w * 32 + (lane >> 3);
  const int sslot = (lane & 7) ^ (lane >> 3);

  f32x4 acc[4][4];
  #pragma unroll
  for (int m = 0; m < 4; ++m)
    #pragma unroll
    for (int n = 0; n < 4; ++n)
      #pragma unroll
      for (int r = 0; r < 4; ++r) acc[m][n][r] = 0.f;

  const ushortT* pA = A16 + (size_t)(m0 + srow) * K + sslot * 8;
  const ushortT* pB = B16 + (size_t)(n0 + srow) * K + sslot * 8;

  auto STAGE = [&](ushortT* buf, int k0) {
    #pragma unroll
    for (int i = 0; i < 4; ++i) {
      const size_t gstep = (size_t)i * 8 * K + k0;
      const int    loff  = (w * 32 + i * 8) * BK;
      gll16(pA + gstep, &buf[loff]);
      gll16(pB + gstep, &buf[8192 + loff]);
    }
  };

  const int arow = wr * 64 + l15;
  const int bcol = wc * 64 + l15;

  auto COMPUTE = [&](const ushortT* buf) {
    const ushortT* sA = buf;
    const ushortT* sB = buf + 8192;
    #pragma unroll
    for (int c = 0; c < 2; ++c) {
      const int slot = c * 4 + g;
      f16x8 af[4], bf[4];
      #pragma unroll
      for (int m = 0; m < 4; ++m) {
        int r   = arow + m * 16;
        int off = r * BK + ((slot ^ (r & 7)) * 8);
        af[m] = *reinterpret_cast<const f16x8*>(&sA[off]);
      }
      #pragma unroll
      for (int n = 0; n < 4; ++n) {
        int r   = bcol + n * 16;
        int off = r * BK + ((slot ^ (r & 7)) * 8);
        bf[n] = *reinterpret_cast<const f16x8*>(&sB[off]);
      }
      #pragma unroll
      for (int m = 0; m < 4; ++m)
        #pragma unroll
        for (int n = 0; n < 4; ++n)
          acc[m][n] = __builtin_amdgcn_mfma_f32_16x16x32_f16(af[m], bf[n], acc[m][n], 0, 0, 0);
    }
  };

  const int nt = K / BK;
  STAGE(&smem[0], 0);
  drain_vmem();
  __syncthreads();
  for (int tt = 0; tt < nt; tt += 2) {
    if (tt + 1 < nt) STAGE(&smem[16384], (tt + 1) * BK);
    COMPUTE(&smem[0]);
    drain_vmem();
    __syncthreads();
    if (tt + 2 < nt) STAGE(&smem[0], (tt + 2) * BK);
    COMPUTE(&smem[16384]);
    drain_vmem();
    __syncthreads();
  }

  #pragma unroll
  for (int n = 0; n < 4; ++n) {
    int col  = n0 + wc * 64 + n * 16 + l15;
    float bv = bias[col];
    #pragma unroll
    for (int m = 0; m < 4; ++m) {
      int row = m0 + wr * 64 + m * 16 + (g << 2);
      #pragma unroll
      for (int r = 0; r < 4; ++r)
        C[(size_t)(row + r) * N + col] = acc[m][n][r] + bv;
    }
  }
}

// ---------------------------------------------------------------------------
// MFMA flash attention — R21 math, re-tiled KB=128 (8 kv-tiles, was 16):
//   * per-tile: 16 QK MFMA + 16 PV + 4 lO (vs 8+8+2 twice) -> barrier and
//     loop overhead per MFMA halves (barriers 32 -> 24).
//   * P ALIASES the K buffer (K fully consumed by QK^T before P exists;
//     one barrier between K-reads and P-writes makes it safe). LDS stays
//     32 KB -> occupancy cap 5 blocks/CU >= grid average 4.
// Accumulation sequence over kv (O, lO) is IDENTICAL to R21; P/Q/K/V values
// unchanged -> bit-identical output (absmax tripwire 4.8828125e-4).
// ---------------------------------------------------------------------------
__global__ __launch_bounds__(256) void attn_mfma(
    const ushortT* __restrict__ Qb, const ushortT* __restrict__ Kb,
    const ushortT* __restrict__ Vt, ushortT* __restrict__ xF)
{
  __shared__ ushortT sKP[128 * 64];   // 16 KB: K [128 kv][64 d] -> P [64 q][128 kv]
  __shared__ ushortT sV[64 * 128];    // 16 KB: V^T [64 d][128 kv]

  const int t    = threadIdx.x;
  const int lane = t & 63;
  const int w    = t >> 6;
  const int bh = blockIdx.x, b = bh >> 4, h = bh & 15;
  const int q0 = blockIdx.y * 64;
  const int l15 = lane & 15;
  const int g   = lane >> 4;

  // Q frags (wave w owns q-rows [q0+w*16, q0+w*16+16)); used as B operand
  f16x8 qa[2];
  #pragma unroll
  for (int ks = 0; ks < 2; ++ks) {
    size_t addr = (size_t)(b * 1024 + q0 + w * 16 + l15) * 1024
                  + h * 64 + ks * 32 + g * 8;
    qa[ks] = *reinterpret_cast<const f16x8*>(&Qb[addr]);
  }

  // all-ones B-frag for l row-sums
  f16x8 ones;
  #pragma unroll
  for (int j = 0; j < 8; ++j) ones[j] = (_Float16)1.0f;

  // K-stage geometry (8-row granule, 64-elem rows)
  const int srowK  = lane >> 3;                 // 0..7
  const int sslotK = (lane & 7) ^ srowK;
  // V-stage geometry (4-row granule, 128-elem rows)
  const int srowV = lane >> 4;                  // 0..3
  const int pV    = lane & 15;

  f32x4 O[4];
  f32x4 lO;
  #pragma unroll
  for (int r = 0; r < 4; ++r) lO[r] = 0.f;
  #pragma unroll
  for (int n = 0; n < 4; ++n)
    #pragma unroll
    for (int r = 0; r < 4; ++r) O[n][r] = 0.f;

  // P-write geometry (swapped layout, [64 q][128 kv])
  const int prow = w * 16 + l15;
  const int pkey = prow & 7;
  const int psub = (g & 1) * 4;
  const int pg2  = g >> 1;

  for (int kt = 0; kt < 8; ++kt) {
    const int k0 = kt * 128;
    // stage K: 4 instrs/wave, rows w*32 + i*8 + srowK (128 rows total)
    #pragma unroll
    for (int i = 0; i < 4; ++i) {
      int r = w * 32 + i * 8 + srowK;
      gll16(&Kb[(size_t)(b * 1024 + k0 + r) * 1024 + h * 64 + sslotK * 8],
            &sKP[(w * 32 + i * 8) * 64]);
    }
    // stage V: 4 instrs/wave, rows w*16 + i*4 + srowV (64 rows total)
    #pragma unroll
    for (int i = 0; i < 4; ++i) {
      int row = w * 16 + i * 4 + srowV;
      int pc  = pV ^ (row & 7);
      gll16(&Vt[((size_t)bh * 64 + row) * 1024 + k0 + pc * 8],
            &sV[(w * 16 + i * 4) * 128]);
    }
    drain_vmem();
    __syncthreads();

    // ---- swapped QK^T: st[n] = P[kv-block n][q], kv = n*16+g*4+r, q = l15
    f32x4 st[8];
    #pragma unroll
    for (int n = 0; n < 8; ++n)
      #pragma unroll
      for (int r = 0; r < 4; ++r) st[n][r] = 0.f;

    #pragma unroll
    for (int ks = 0; ks < 2; ++ks) {
      f16x8 kb[8];
      #pragma unroll
      for (int n = 0; n < 8; ++n) {
        int row = n * 16 + l15;
        kb[n] = *reinterpret_cast<const f16x8*>(
            &sKP[row * 64 + (((g + ks * 4) ^ (row & 7)) * 8)]);
      }
      #pragma unroll
      for (int n = 0; n < 8; ++n)
        st[n] = __builtin_amdgcn_mfma_f32_16x16x32_f16(kb[n], qa[ks], st[n], 0, 0, 0);
    }
    __syncthreads();   // all K reads complete before P overwrites sKP

    // ---- softmax numerators + packed b64 P-writes (8 per thread)
    #pragma unroll
    for (int n = 0; n < 8; ++n) {
      ushortT p4[4];
      #pragma unroll
      for (int r = 0; r < 4; ++r)
        p4[r] = f2h_bits(exp2f(st[n][r]));
      uint2v pk;
      pk.x = (unsigned)p4[0] | ((unsigned)p4[1] << 16);
      pk.y = (unsigned)p4[2] | ((unsigned)p4[3] << 16);
      int cs = n * 2 + pg2;                    // chunk 0..15
      *reinterpret_cast<uint2v*>(
          &sKP[prow * 128 + ((cs ^ pkey) << 3) + psub]) = pk;
    }

    // ---- PV over 128 kv (4 ks slots); pa reads own-wave P rows
    #pragma unroll
    for (int ks = 0; ks < 4; ++ks) {
      f16x8 vb[4], pa;
      #pragma unroll
      for (int n = 0; n < 4; ++n) {
        int rd = n * 16 + l15;
        vb[n] = *reinterpret_cast<const f16x8*>(
            &sV[rd * 128 + (((ks * 4 + g) ^ (rd & 7)) * 8)]);
      }
      pa = *reinterpret_cast<const f16x8*>(
          &sKP[prow * 128 + (((ks * 4 + g) ^ pkey) * 8)]);
      #pragma unroll
      for (int n = 0; n < 4; ++n)
        O[n] = __builtin_amdgcn_mfma_f32_16x16x32_f16(pa, vb[n], O[n], 0, 0, 0);
      lO = __builtin_amdgcn_mfma_f32_16x16x32_f16(pa, ones, lO, 0, 0, 0);
    }
    __syncthreads();   // PV reads done before next tile's stage
  }

  // epilogue: lO[r] holds l[q] (replicated across the 16 col-lanes)
  #pragma unroll
  for (int r = 0; r < 4; ++r) {
    float inv = 1.f / lO[r];
    #pragma unroll
    for (int n = 0; n < 4; ++n) {
      size_t off = (size_t)(b * 1024 + q0 + w * 16 + g * 4 + r) * 1024
                   + h * 64 + n * 16 + l15;
      xF[off] = f2h_bits(O[n][r] * inv);
    }
  }
}

// ---------------------------------------------------------------------------
extern "C" void kernel_launch(void* const* d_in, const int* in_sizes, int n_in,
                              void* d_out, int out_size, void* d_ws, size_t ws_size,
                              hipStream_t stream) {
  const float* hs = (const float*)d_in[0];   // [B,S,NX]
  const float* aw = (const float*)d_in[1];   // [NX, 3NX]
  const float* ab = (const float*)d_in[2];   // [3NX]
  const float* pw = (const float*)d_in[3];   // [NX, NX]
  const float* pb = (const float*)d_in[4];   // [NX]
  float* out = (float*)d_out;                // [B,S,NX]

  char* ws = (char*)d_ws;
  const int M = Bb * Ss;                     // 4096

  // workspace (~50 MB):
  ushortT* hF  = (ushortT*)(ws);                       //  8 MB fp16 hs
  ushortT* awT = (ushortT*)(ws + ( 8u << 20));         //  6 MB fp16 attn W^T
  ushortT* pwT = (ushortT*)(ws + (14u << 20));         //  2 MB fp16 proj W^T
  ushortT* Qb  = (ushortT*)(ws + (18u << 20));         //  8 MB fp16
  ushortT* Kb  = (ushortT*)(ws + (26u << 20));         //  8 MB fp16
  ushortT* Vt  = (ushortT*)(ws + (34u << 20));         //  8 MB fp16
  ushortT* xF  = (ushortT*)(ws + (42u << 20));         //  8 MB fp16 attn out

  dim3 blk(256);

  // 1) fused preps: hs->fp16, aw->fp16^T, pw->fp16^T
  prep_all<<<8192, blk, 0, stream>>>(hs, aw, pw, hF, awT, pwT);
  // 2) fused fp16 QKV GEMM (2-phase dbuf, XCD swizzle) -> Qb, Kb, Vt (fp16)
  gemm_f16_qkv<<<dim3(24, 32), blk, 0, stream>>>(
      hF, awT, ab, Qb, Kb, Vt, M, 3 * NXc, NXc);
  // 3) MFMA flash attention (KB=128, P-aliases-K) -> fp16 xF
  attn_mfma<<<dim3(Bb * NHc, Ss / 64), blk, 0, stream>>>(Qb, Kb, Vt, xF);
  // 4) out = xF @ c_proj_w + b (single-pass fp16, 2-phase dbuf, XCD swizzle)
  gemm_f16s<<<dim3(8, 32), blk, 0, stream>>>(
      xF, pwT, pb, out, M, NXc, NXc);
}

// Round 23
// 97.559 us; speedup vs baseline: 1.0311x; 1.0311x over previous
//
#include <hip/hip_runtime.h>
#include <hip/hip_fp16.h>
#include <cmath>

// Problem constants: B=4, S=1024, NX=1024, NH=16, HD=64
constexpr int Bb  = 4;
constexpr int Ss  = 1024;
constexpr int NXc = 1024;
constexpr int NHc = 16;
constexpr int HDc = 64;

typedef __bf16    bf16x8 __attribute__((ext_vector_type(8)));
typedef _Float16  f16x8  __attribute__((ext_vector_type(8)));
typedef float     f32x4  __attribute__((ext_vector_type(4)));
typedef unsigned short ushortT;
typedef ushortT ushort8v __attribute__((ext_vector_type(8)));
typedef unsigned uint2v  __attribute__((ext_vector_type(2)));

// Q pre-scale: (1/sqrt(64)) * log2(e) -> softmax via single v_exp_f32 (exp2)
#define QSCALE 0.18033688011112042f

// ---------------------------------------------------------------------------
// helpers
// ---------------------------------------------------------------------------
__device__ __forceinline__ ushortT f2h_bits(float x) {
  return __half_as_ushort(__float2half(x));   // RNE, single v_cvt_f16_f32
}

// async global->LDS, 16 bytes per lane
__device__ __forceinline__ void gll16(const void* g, void* l) {
  __builtin_amdgcn_global_load_lds(
      (const __attribute__((address_space(1))) unsigned int*)g,
      (__attribute__((address_space(3))) unsigned int*)l, 16, 0, 0);
}

// explicit drain of all outstanding VMEM (incl. global_load_lds DMA)
__device__ __forceinline__ void drain_vmem() {
  asm volatile("s_waitcnt vmcnt(0)" ::: "memory");
  __builtin_amdgcn_sched_barrier(0);
}

// ---------------------------------------------------------------------------
// Fused prep kernel (deterministic: block-local, uniform branches):
//   blocks [0,4096):     hs fp32 -> fp16 (hF)
//   blocks [4096,7168):  aw [1024][3072] -> transposed fp16 awT [3072][1024]
//   blocks [7168,8192):  pw [1024][1024] -> transposed fp16 pwT [1024][1024]
// ---------------------------------------------------------------------------
__global__ __launch_bounds__(256) void prep_all(
    const float* __restrict__ hs, const float* __restrict__ aw,
    const float* __restrict__ pw,
    ushortT* __restrict__ hF, ushortT* __restrict__ awT,
    ushortT* __restrict__ pwT)
{
  const int bid = blockIdx.x;
  if (bid < 4096) {
    int i = (bid * 256 + threadIdx.x) * 4;
    float4 v = *reinterpret_cast<const float4*>(&hs[i]);
    *reinterpret_cast<ushort4*>(&hF[i]) =
        make_ushort4(f2h_bits(v.x), f2h_bits(v.y), f2h_bits(v.z), f2h_bits(v.w));
    return;
  }
  __shared__ float tile[32][33];
  const int tx = threadIdx.x & 31, ty = threadIdx.x >> 5;  // 32 x 8
  if (bid < 7168) {
    // aw transpose: K=1024, N=3072
    const int b2 = bid - 4096;
    const int n0 = (b2 % 96) * 32, k0 = (b2 / 96) * 32;
    #pragma unroll
    for (int i = 0; i < 4; ++i)
      tile[ty + i * 8][tx] = aw[(size_t)(k0 + ty + i * 8) * 3072 + n0 + tx];
    __syncthreads();
    #pragma unroll
    for (int i = 0; i < 4; ++i)
      awT[(size_t)(n0 + ty + i * 8) * 1024 + k0 + tx] = f2h_bits(tile[tx][ty + i * 8]);
  } else {
    // pw transpose: K=1024, N=1024
    const int b2 = bid - 7168;
    const int n0 = (b2 & 31) * 32, k0 = (b2 >> 5) * 32;
    #pragma unroll
    for (int i = 0; i < 4; ++i)
      tile[ty + i * 8][tx] = pw[(size_t)(k0 + ty + i * 8) * 1024 + n0 + tx];
    __syncthreads();
    #pragma unroll
    for (int i = 0; i < 4; ++i)
      pwT[(size_t)(n0 + ty + i * 8) * 1024 + k0 + tx] = f2h_bits(tile[tx][ty + i * 8]);
  }
}

// ---------------------------------------------------------------------------
// Single-pass fp16 MFMA GEMM with fused QKV epilogue (R19-R21-verified,
// incl. XCD-bijective swizzle). Outputs fp16 Qb (x QSCALE), Kb, Vt.
// ---------------------------------------------------------------------------
__global__ __launch_bounds__(256) void gemm_f16_qkv(
    const ushortT* __restrict__ A16, const ushortT* __restrict__ B16,
    const float* __restrict__ bias,
    ushortT* __restrict__ Qb, ushortT* __restrict__ Kb,
    ushortT* __restrict__ Vt, int M, int N, int K)
{
  constexpr int BK = 64;
  __shared__ ushortT smem[32768];   // 64 KB: buf0 [0,16384), buf1 [16384,32768)

  const int t    = threadIdx.x;
  const int lane = t & 63;
  const int w    = t >> 6;
  const int wr   = w >> 1, wc = w & 1;
  const int lin = blockIdx.y * 24 + blockIdx.x;           // 0..767
  const int swz = (lin & 7) * 96 + (lin >> 3);
  const int m0 = (swz / 24) * 128;
  const int n0 = (swz % 24) * 128;
  const int l15 = lane & 15;
  const int g   = lane >> 4;

  const int srow  = w * 32 + (lane >> 3);
  const int sslot = (lane & 7) ^ (lane >> 3);

  f32x4 acc[4][4];
  #pragma unroll
  for (int m = 0; m < 4; ++m)
    #pragma unroll
    for (int n = 0; n < 4; ++n)
      #pragma unroll
      for (int r = 0; r < 4; ++r) acc[m][n][r] = 0.f;

  const ushortT* pA = A16 + (size_t)(m0 + srow) * K + sslot * 8;
  const ushortT* pB = B16 + (size_t)(n0 + srow) * K + sslot * 8;

  auto STAGE = [&](ushortT* buf, int k0) {
    #pragma unroll
    for (int i = 0; i < 4; ++i) {
      const size_t gstep = (size_t)i * 8 * K + k0;
      const int    loff  = (w * 32 + i * 8) * BK;
      gll16(pA + gstep, &buf[loff]);
      gll16(pB + gstep, &buf[8192 + loff]);
    }
  };

  const int arow = wr * 64 + l15;
  const int bcol = wc * 64 + l15;

  auto COMPUTE = [&](const ushortT* buf) {
    const ushortT* sA = buf;
    const ushortT* sB = buf + 8192;
    #pragma unroll
    for (int c = 0; c < 2; ++c) {
      const int slot = c * 4 + g;
      f16x8 af[4], bf[4];
      #pragma unroll
      for (int m = 0; m < 4; ++m) {
        int r   = arow + m * 16;
        int off = r * BK + ((slot ^ (r & 7)) * 8);
        af[m] = *reinterpret_cast<const f16x8*>(&sA[off]);
      }
      #pragma unroll
      for (int n = 0; n < 4; ++n) {
        int r   = bcol + n * 16;
        int off = r * BK + ((slot ^ (r & 7)) * 8);
        bf[n] = *reinterpret_cast<const f16x8*>(&sB[off]);
      }
      #pragma unroll
      for (int m = 0; m < 4; ++m)
        #pragma unroll
        for (int n = 0; n < 4; ++n)
          acc[m][n] = __builtin_amdgcn_mfma_f32_16x16x32_f16(af[m], bf[n], acc[m][n], 0, 0, 0);
    }
  };

  const int nt = K / BK;
  STAGE(&smem[0], 0);
  drain_vmem();
  __syncthreads();
  for (int tt = 0; tt < nt; tt += 2) {
    if (tt + 1 < nt) STAGE(&smem[16384], (tt + 1) * BK);
    COMPUTE(&smem[0]);
    drain_vmem();
    __syncthreads();
    if (tt + 2 < nt) STAGE(&smem[0], (tt + 2) * BK);
    COMPUTE(&smem[16384]);
    drain_vmem();
    __syncthreads();
  }

  const int region = n0 >> 10;   // 0=Q, 1=K, 2=V
  if (region < 2) {
    #pragma unroll
    for (int n = 0; n < 4; ++n) {
      int col_g = n0 + wc * 64 + n * 16 + l15;
      int colm  = col_g & 1023;
      float bv  = bias[col_g];
      #pragma unroll
      for (int m = 0; m < 4; ++m) {
        int row = m0 + wr * 64 + m * 16 + (g << 2);
        #pragma unroll
        for (int r = 0; r < 4; ++r) {
          float v = acc[m][n][r] + bv;
          if (region == 0)
            Qb[(size_t)(row + r) * 1024 + colm] = f2h_bits(v * QSCALE);
          else
            Kb[(size_t)(row + r) * 1024 + colm] = f2h_bits(v);
        }
      }
    }
  } else {
    ushortT* T = smem;   // [128 cols][136] = 34816 B <= 64 KB
    #pragma unroll
    for (int n = 0; n < 4; ++n) {
      int cl   = wc * 64 + n * 16 + l15;
      float bv = bias[n0 + cl];
      #pragma unroll
      for (int m = 0; m < 4; ++m) {
        int rl = wr * 64 + m * 16 + (g << 2);
        #pragma unroll
        for (int r = 0; r < 4; ++r)
          T[cl * 136 + rl + r] = f2h_bits(acc[m][n][r] + bv);
      }
    }
    __syncthreads();
    const int c  = t >> 1;
    const int rh = (t & 1) * 64;
    const int nn = (n0 - 2048) + c;
    const int hh = nn >> 6, dd = nn & 63;
    const int bb = m0 >> 10;
    const int sl = (m0 & 1023) + rh;
    size_t vbase = ((size_t)((bb * 16 + hh) * 64 + dd)) * 1024 + sl;
    #pragma unroll
    for (int j = 0; j < 8; ++j) {
      ushort8v v = *reinterpret_cast<const ushort8v*>(&T[c * 136 + rh + j * 8]);
      *reinterpret_cast<ushort8v*>(&Vt[vbase + j * 8]) = v;
    }
  }
}

// ---------------------------------------------------------------------------
// Single-pass fp16 MFMA GEMM (proj), 2-phase dbuf + XCD swizzle (R19-R21).
// ---------------------------------------------------------------------------
__global__ __launch_bounds__(256) void gemm_f16s(
    const ushortT* __restrict__ A16, const ushortT* __restrict__ B16,
    const float* __restrict__ bias, float* __restrict__ C,
    int M, int N, int K)
{
  constexpr int BK = 64;
  __shared__ ushortT smem[32768];   // 64 KB: two 32KB buffers

  const int t    = threadIdx.x;
  const int lane = t & 63;
  const int w    = t >> 6;
  const int wr   = w >> 1, wc = w & 1;
  const int lin = blockIdx.y * 8 + blockIdx.x;            // 0..255
  const int swz = (lin & 7) * 32 + (lin >> 3);
  const int m0 = (swz / 8) * 128;
  const int n0 = (swz % 8) * 128;
  const int l15 = lane & 15;
  const int g   = lane >> 4;

  const int srow  = w * 32 + (lane >> 3);
  const int sslot = (lane & 7) ^ (lane >> 3);

  f32x4 acc[4][4];
  #pragma unroll
  for (int m = 0; m < 4; ++m)
    #pragma unroll
    for (int n = 0; n < 4; ++n)
      #pragma unroll
      for (int r = 0; r < 4; ++r) acc[m][n][r] = 0.f;

  const ushortT* pA = A16 + (size_t)(m0 + srow) * K + sslot * 8;
  const ushortT* pB = B16 + (size_t)(n0 + srow) * K + sslot * 8;

  auto STAGE = [&](ushortT* buf, int k0) {
    #pragma unroll
    for (int i = 0; i < 4; ++i) {
      const size_t gstep = (size_t)i * 8 * K + k0;
      const int    loff  = (w * 32 + i * 8) * BK;
      gll16(pA + gstep, &buf[loff]);
      gll16(pB + gstep, &buf[8192 + loff]);
    }
  };

  const int arow = wr * 64 + l15;
  const int bcol = wc * 64 + l15;

  auto COMPUTE = [&](const ushortT* buf) {
    const ushortT* sA = buf;
    const ushortT* sB = buf + 8192;
    #pragma unroll
    for (int c = 0; c < 2; ++c) {
      const int slot = c * 4 + g;
      f16x8 af[4], bf[4];
      #pragma unroll
      for (int m = 0; m < 4; ++m) {
        int r   = arow + m * 16;
        int off = r * BK + ((slot ^ (r & 7)) * 8);
        af[m] = *reinterpret_cast<const f16x8*>(&sA[off]);
      }
      #pragma unroll
      for (int n = 0; n < 4; ++n) {
        int r   = bcol + n * 16;
        int off = r * BK + ((slot ^ (r & 7)) * 8);
        bf[n] = *reinterpret_cast<const f16x8*>(&sB[off]);
      }
      #pragma unroll
      for (int m = 0; m < 4; ++m)
        #pragma unroll
        for (int n = 0; n < 4; ++n)
          acc[m][n] = __builtin_amdgcn_mfma_f32_16x16x32_f16(af[m], bf[n], acc[m][n], 0, 0, 0);
    }
  };

  const int nt = K / BK;
  STAGE(&smem[0], 0);
  drain_vmem();
  __syncthreads();
  for (int tt = 0; tt < nt; tt += 2) {
    if (tt + 1 < nt) STAGE(&smem[16384], (tt + 1) * BK);
    COMPUTE(&smem[0]);
    drain_vmem();
    __syncthreads();
    if (tt + 2 < nt) STAGE(&smem[0], (tt + 2) * BK);
    COMPUTE(&smem[16384]);
    drain_vmem();
    __syncthreads();
  }

  #pragma unroll
  for (int n = 0; n < 4; ++n) {
    int col  = n0 + wc * 64 + n * 16 + l15;
    float bv = bias[col];
    #pragma unroll
    for (int m = 0; m < 4; ++m) {
      int row = m0 + wr * 64 + m * 16 + (g << 2);
      #pragma unroll
      for (int r = 0; r < 4; ++r)
        C[(size_t)(row + r) * N + col] = acc[m][n][r] + bv;
    }
  }
}

// ---------------------------------------------------------------------------
// MFMA flash attention — R21-verified (best config): QB=64, 16 kv-tiles,
// single-buf staging, XCD-local grid, no setprio, ones-MFMA l,
// swapped QK^T (D[kv][q]) + packed b64 P-writes.
// ---------------------------------------------------------------------------
__global__ __launch_bounds__(256) void attn_mfma(
    const ushortT* __restrict__ Qb, const ushortT* __restrict__ Kb,
    const ushortT* __restrict__ Vt, ushortT* __restrict__ xF)
{
  __shared__ ushortT sK[64 * 64];   // 8 KB
  __shared__ ushortT sV[64 * 64];   // 8 KB
  __shared__ ushortT sP[64 * 64];   // 8 KB

  const int t    = threadIdx.x;
  const int lane = t & 63;
  const int w    = t >> 6;
  const int bh = blockIdx.x, b = bh >> 4, h = bh & 15;
  const int q0 = blockIdx.y * 64;
  const int l15 = lane & 15;
  const int g   = lane >> 4;

  // Q frags (wave w owns q-rows [q0+w*16, q0+w*16+16)); used as B operand
  f16x8 qa[2];
  #pragma unroll
  for (int ks = 0; ks < 2; ++ks) {
    size_t addr = (size_t)(b * 1024 + q0 + w * 16 + l15) * 1024
                  + h * 64 + ks * 32 + g * 8;
    qa[ks] = *reinterpret_cast<const f16x8*>(&Qb[addr]);
  }

  // all-ones B-frag for l row-sums
  f16x8 ones;
  #pragma unroll
  for (int j = 0; j < 8; ++j) ones[j] = (_Float16)1.0f;

  const int srow  = lane >> 3;
  const int sslot = (lane & 7) ^ srow;

  f32x4 O[4];
  f32x4 lO;
  #pragma unroll
  for (int r = 0; r < 4; ++r) lO[r] = 0.f;
  #pragma unroll
  for (int n = 0; n < 4; ++n)
    #pragma unroll
    for (int r = 0; r < 4; ++r) O[n][r] = 0.f;

  // P-write geometry (swapped layout): row q = w*16+l15 (wave-private),
  // chunk slot = n*2+(g>>1), sub-offset (g&1)*4, XOR-swizzled per row.
  const int prow  = w * 16 + l15;
  const int pbase = prow * 64 + (g & 1) * 4;
  const int pcs0  = g >> 1;            // chunk-slot contribution from g

  for (int kt = 0; kt < 16; ++kt) {
    const int k0 = kt * 64;
    #pragma unroll
    for (int i = 0; i < 2; ++i) {
      int r = w * 16 + i * 8 + srow;
      gll16(&Kb[(size_t)(b * 1024 + k0 + r) * 1024 + h * 64 + sslot * 8],
            &sK[(w * 16 + i * 8) * 64]);
      gll16(&Vt[((size_t)bh * 64 + r) * 1024 + k0 + sslot * 8],
            &sV[(w * 16 + i * 8) * 64]);
    }
    __syncthreads();

    // ---- swapped QK^T: st[n] = P[kv-block n][q], kv = n*16+g*4+r, q = l15
    f32x4 st[4];
    #pragma unroll
    for (int n = 0; n < 4; ++n)
      #pragma unroll
      for (int r = 0; r < 4; ++r) st[n][r] = 0.f;

    #pragma unroll
    for (int ks = 0; ks < 2; ++ks) {
      f16x8 kb[4];
      #pragma unroll
      for (int n = 0; n < 4; ++n) {
        int row = n * 16 + l15;
        kb[n] = *reinterpret_cast<const f16x8*>(
            &sK[row * 64 + (((g + ks * 4) ^ (row & 7)) * 8)]);
      }
      #pragma unroll
      for (int n = 0; n < 4; ++n)
        st[n] = __builtin_amdgcn_mfma_f32_16x16x32_f16(kb[n], qa[ks], st[n], 0, 0, 0);
    }

    // ---- softmax numerators + packed b64 P-writes (4 per thread)
    #pragma unroll
    for (int n = 0; n < 4; ++n) {
      ushortT p4[4];
      #pragma unroll
      for (int r = 0; r < 4; ++r)
        p4[r] = f2h_bits(exp2f(st[n][r]));
      uint2v pk;
      pk.x = (unsigned)p4[0] | ((unsigned)p4[1] << 16);
      pk.y = (unsigned)p4[2] | ((unsigned)p4[3] << 16);
      int cs = n * 2 + pcs0;
      *reinterpret_cast<uint2v*>(&sP[pbase + ((cs ^ (prow & 7)) << 3)]) = pk;
    }

    #pragma unroll
    for (int ks = 0; ks < 2; ++ks) {
      f16x8 vb[4], pa;
      #pragma unroll
      for (int n = 0; n < 4; ++n) {
        int rd = n * 16 + l15;
        vb[n] = *reinterpret_cast<const f16x8*>(
            &sV[rd * 64 + (((g + ks * 4) ^ (rd & 7)) * 8)]);
      }
      {
        int pr = w * 16 + l15;
        pa = *reinterpret_cast<const f16x8*>(
            &sP[pr * 64 + (((g + ks * 4) ^ (pr & 7)) * 8)]);
      }
      #pragma unroll
      for (int n = 0; n < 4; ++n)
        O[n] = __builtin_amdgcn_mfma_f32_16x16x32_f16(pa, vb[n], O[n], 0, 0, 0);
      lO = __builtin_amdgcn_mfma_f32_16x16x32_f16(pa, ones, lO, 0, 0, 0);
    }
    __syncthreads();
  }

  // epilogue: lO[r] holds l[q] (replicated across the 16 col-lanes)
  #pragma unroll
  for (int r = 0; r < 4; ++r) {
    float inv = 1.f / lO[r];
    #pragma unroll
    for (int n = 0; n < 4; ++n) {
      size_t off = (size_t)(b * 1024 + q0 + w * 16 + g * 4 + r) * 1024
                   + h * 64 + n * 16 + l15;
      xF[off] = f2h_bits(O[n][r] * inv);
    }
  }
}

// ---------------------------------------------------------------------------
extern "C" void kernel_launch(void* const* d_in, const int* in_sizes, int n_in,
                              void* d_out, int out_size, void* d_ws, size_t ws_size,
                              hipStream_t stream) {
  const float* hs = (const float*)d_in[0];   // [B,S,NX]
  const float* aw = (const float*)d_in[1];   // [NX, 3NX]
  const float* ab = (const float*)d_in[2];   // [3NX]
  const float* pw = (const float*)d_in[3];   // [NX, NX]
  const float* pb = (const float*)d_in[4];   // [NX]
  float* out = (float*)d_out;                // [B,S,NX]

  char* ws = (char*)d_ws;
  const int M = Bb * Ss;                     // 4096

  // workspace (~50 MB):
  ushortT* hF  = (ushortT*)(ws);                       //  8 MB fp16 hs
  ushortT* awT = (ushortT*)(ws + ( 8u << 20));         //  6 MB fp16 attn W^T
  ushortT* pwT = (ushortT*)(ws + (14u << 20));         //  2 MB fp16 proj W^T
  ushortT* Qb  = (ushortT*)(ws + (18u << 20));         //  8 MB fp16
  ushortT* Kb  = (ushortT*)(ws + (26u << 20));         //  8 MB fp16
  ushortT* Vt  = (ushortT*)(ws + (34u << 20));         //  8 MB fp16
  ushortT* xF  = (ushortT*)(ws + (42u << 20));         //  8 MB fp16 attn out

  dim3 blk(256);

  // 1) fused preps: hs->fp16, aw->fp16^T, pw->fp16^T
  prep_all<<<8192, blk, 0, stream>>>(hs, aw, pw, hF, awT, pwT);
  // 2) fused fp16 QKV GEMM (2-phase dbuf, XCD swizzle) -> Qb, Kb, Vt (fp16)
  gemm_f16_qkv<<<dim3(24, 32), blk, 0, stream>>>(
      hF, awT, ab, Qb, Kb, Vt, M, 3 * NXc, NXc);
  // 3) MFMA flash attention (swapped QK^T, packed P-writes) -> fp16 xF
  attn_mfma<<<dim3(Bb * NHc, Ss / 64), blk, 0, stream>>>(Qb, Kb, Vt, xF);
  // 4) out = xF @ c_proj_w + b (single-pass fp16, 2-phase dbuf, XCD swizzle)
  gemm_f16s<<<dim3(8, 32), blk, 0, stream>>>(
      xF, pwT, pb, out, M, NXc, NXc);
}